// Round 3
// baseline (432.030 us; speedup 1.0000x reference)
//
#include <hip/hip_runtime.h>
#include <hip/hip_bf16.h>

// EdgePredict: out = softmax((h[u]*h[v]) @ W1 @ W2 @ W3 + biases)
// R0: linear MLP chain collapses to wd[256] + bd (2-class softmax = sigmoid of
//     logit diff).
// R2: bf16 table in ws halves gather bytes. Observed: duration tracks CACHE-
//     LINE REQUESTS (~107 G lines/s both rounds), not bytes.
// R3: counting-sort edges by u -> each wave processes a contiguous u-run, so
//     u-rows hit the per-CU L1 (8 lines/edge -> ~0.8). Line requests/edge
//     16.25 -> ~10. Predicted edge kernel ~95-105 us.

#define D 256
#define DV (D / 4)   // float4 per row
#define RU2 (D / 4)  // uint2 per row = 64 (4 bf16 each)

// ---------------------------------------------------------------------------
__device__ __forceinline__ unsigned bf16rn(float f) {
    unsigned u = __float_as_uint(f);
    u += 0x7fffu + ((u >> 16) & 1u);
    return u >> 16;
}
__device__ __forceinline__ float blo(unsigned u) { return __uint_as_float(u << 16); }
__device__ __forceinline__ float bhi(unsigned u) { return __uint_as_float(u & 0xffff0000u); }

// ---------------------------------------------------------------------------
// prep: zero histogram + convert h -> bf16 table; block 0 also collapses the
// weight chain into wd[256], bd.
// ---------------------------------------------------------------------------
__global__ __launch_bounds__(256) void prep(
    const float4* __restrict__ h, uint2* __restrict__ hb, int nvec,
    const float* __restrict__ W1, const float* __restrict__ b1,
    const float* __restrict__ W2, const float* __restrict__ b2,
    const float* __restrict__ W3, const float* __restrict__ b3,
    float* __restrict__ wc, int* __restrict__ hist, int nhp)
{
    const int gstride = gridDim.x * blockDim.x;
    for (int i = blockIdx.x * blockDim.x + threadIdx.x; i < nhp; i += gstride)
        hist[i] = 0;

    if (blockIdx.x == 0) {
        __shared__ float T[128][2];  // T = W2 @ W3
        const int t = threadIdx.x;
        {
            const int j = t >> 1, c = t & 1;
            float s = 0.f;
            #pragma unroll 8
            for (int k = 0; k < 64; ++k) s += W2[j * 64 + k] * W3[k * 2 + c];
            T[j][c] = s;
        }
        __syncthreads();
        float s0 = 0.f, s1 = 0.f;
        #pragma unroll 8
        for (int j = 0; j < 128; ++j) {
            const float w = W1[t * 128 + j];
            s0 += w * T[j][0];
            s1 += w * T[j][1];
        }
        wc[t] = s1 - s0;
        if (t == 0) {
            float f0 = b3[0], f1 = b3[1];
            for (int j = 0; j < 128; ++j) { f0 += b1[j] * T[j][0]; f1 += b1[j] * T[j][1]; }
            for (int k = 0; k < 64; ++k)  { f0 += b2[k] * W3[k * 2 + 0]; f1 += b2[k] * W3[k * 2 + 1]; }
            wc[256] = f1 - f0;
        }
    }

    for (int i = blockIdx.x * blockDim.x + threadIdx.x; i < nvec; i += gstride) {
        const float4 f = h[i];
        uint2 o;
        o.x = bf16rn(f.x) | (bf16rn(f.y) << 16);
        o.y = bf16rn(f.z) | (bf16rn(f.w) << 16);
        hb[i] = o;
    }
}

// ---------------------------------------------------------------------------
// counting sort by u:  hist -> scan(3 kernels) -> scatter
// ---------------------------------------------------------------------------
__global__ __launch_bounds__(256) void hist_k(
    const int2* __restrict__ edges, int* __restrict__ hist, int E)
{
    const int gstride = gridDim.x * blockDim.x;
    for (int e = blockIdx.x * blockDim.x + threadIdx.x; e < E; e += gstride)
        atomicAdd(&hist[edges[e].x], 1);
}

__global__ __launch_bounds__(256) void scan1(
    const int* __restrict__ in, int* __restrict__ outp, int* __restrict__ aux, int n)
{
    __shared__ int buf[2][256];
    const int t = threadIdx.x;
    const int gid = blockIdx.x * 256 + t;
    const int v = (gid < n) ? in[gid] : 0;
    buf[0][t] = v;
    __syncthreads();
    int src = 0;
    for (int off = 1; off < 256; off <<= 1) {
        int val = buf[src][t];
        if (t >= off) val += buf[src][t - off];
        buf[src ^ 1][t] = val;
        src ^= 1;
        __syncthreads();
    }
    if (gid < n) outp[gid] = buf[src][t] - v;  // exclusive
    if (t == 255) aux[blockIdx.x] = buf[src][t];
}

__global__ __launch_bounds__(256) void scan2(int* __restrict__ aux, int n)
{
    __shared__ int buf[2][256];
    const int t = threadIdx.x;
    int v[4];
    const int base = t * 4;
    for (int k = 0; k < 4; ++k) { const int i = base + k; v[k] = (i < n) ? aux[i] : 0; }
    const int local = v[0] + v[1] + v[2] + v[3];
    buf[0][t] = local;
    __syncthreads();
    int src = 0;
    for (int off = 1; off < 256; off <<= 1) {
        int val = buf[src][t];
        if (t >= off) val += buf[src][t - off];
        buf[src ^ 1][t] = val;
        src ^= 1;
        __syncthreads();
    }
    int run = buf[src][t] - local;  // exclusive over groups
    for (int k = 0; k < 4; ++k) { const int i = base + k; if (i < n) aux[i] = run; run += v[k]; }
}

__global__ __launch_bounds__(256) void scan3(
    int* __restrict__ cursor, const int* __restrict__ aux, int n)
{
    const int gstride = gridDim.x * blockDim.x;
    for (int i = blockIdx.x * blockDim.x + threadIdx.x; i < n; i += gstride)
        cursor[i] += aux[i >> 8];
}

__global__ __launch_bounds__(256) void scatter_k(
    const int2* __restrict__ edges, int* __restrict__ cursor,
    int2* __restrict__ puv, int* __restrict__ pidx, int E)
{
    const int gstride = gridDim.x * blockDim.x;
    for (int e = blockIdx.x * blockDim.x + threadIdx.x; e < E; e += gstride) {
        const int2 ed = edges[e];
        const int pos = atomicAdd(&cursor[ed.x], 1);
        puv[pos] = ed;
        pidx[pos] = e;
    }
}

// ---------------------------------------------------------------------------
// Sorted edge kernel: each wave owns a contiguous chunk of the u-sorted edge
// list; repeated u-rows hit L1. One wave per edge-slot, 2-edge unroll for MLP.
// ---------------------------------------------------------------------------
__global__ __launch_bounds__(256) void edge_sorted(
    const uint2* __restrict__ hb, const int2* __restrict__ puv,
    const int* __restrict__ pidx, const float* __restrict__ wc,
    float2* __restrict__ out, int E, int chunk)
{
    const int lane = threadIdx.x & 63;
    const int wid  = blockIdx.x * (blockDim.x >> 6) + (threadIdx.x >> 6);
    const int s    = wid * chunk;
    const int eend = min(E, s + chunk);

    const float4 wd = ((const float4*)wc)[lane];
    const float  bd = wc[256];

    int e = s;
    for (; e + 1 < eend; e += 2) {
        const int2 ed1 = puv[e];
        const int2 ed2 = puv[e + 1];
        const uint2 ua1 = hb[(size_t)ed1.x * RU2 + lane];
        const uint2 ub1 = hb[(size_t)ed1.y * RU2 + lane];
        const uint2 ua2 = hb[(size_t)ed2.x * RU2 + lane];
        const uint2 ub2 = hb[(size_t)ed2.y * RU2 + lane];

        float d1 = blo(ua1.x) * blo(ub1.x) * wd.x + bhi(ua1.x) * bhi(ub1.x) * wd.y
                 + blo(ua1.y) * blo(ub1.y) * wd.z + bhi(ua1.y) * bhi(ub1.y) * wd.w;
        float d2 = blo(ua2.x) * blo(ub2.x) * wd.x + bhi(ua2.x) * bhi(ub2.x) * wd.y
                 + blo(ua2.y) * blo(ub2.y) * wd.z + bhi(ua2.y) * bhi(ub2.y) * wd.w;
        #pragma unroll
        for (int m = 32; m > 0; m >>= 1) {
            d1 += __shfl_xor(d1, m, 64);
            d2 += __shfl_xor(d2, m, 64);
        }
        if (lane == 0) {
            const float p1 = 1.0f / (1.0f + __expf(-(d1 + bd)));
            out[pidx[e]] = make_float2(1.0f - p1, p1);
            const float p2 = 1.0f / (1.0f + __expf(-(d2 + bd)));
            out[pidx[e + 1]] = make_float2(1.0f - p2, p2);
        }
    }
    if (e < eend) {
        const int2 ed = puv[e];
        const uint2 ua = hb[(size_t)ed.x * RU2 + lane];
        const uint2 ub = hb[(size_t)ed.y * RU2 + lane];
        float d = blo(ua.x) * blo(ub.x) * wd.x + bhi(ua.x) * bhi(ub.x) * wd.y
                + blo(ua.y) * blo(ub.y) * wd.z + bhi(ua.y) * bhi(ub.y) * wd.w;
        #pragma unroll
        for (int m = 32; m > 0; m >>= 1) d += __shfl_xor(d, m, 64);
        if (lane == 0) {
            const float p1 = 1.0f / (1.0f + __expf(-(d + bd)));
            out[pidx[e]] = make_float2(1.0f - p1, p1);
        }
    }
}

// ---------------------------------------------------------------------------
// Fallbacks (R2 path / fp32 path) if ws is too small for the sort buffers.
// ---------------------------------------------------------------------------
__global__ __launch_bounds__(256) void edge_predict_bf16(
    const uint2* __restrict__ hb, const int2* __restrict__ edges,
    const float* __restrict__ wc, float2* __restrict__ out, int E)
{
    const int lane = threadIdx.x & 63;
    const int wid  = blockIdx.x * (blockDim.x >> 6) + (threadIdx.x >> 6);
    const int nw   = gridDim.x * (blockDim.x >> 6);
    const float4 wd = ((const float4*)wc)[lane];
    const float  bd = wc[256];
    for (int e = wid; e < E; e += nw) {
        const int2 ed = edges[e];
        const uint2 ua = hb[(size_t)ed.x * RU2 + lane];
        const uint2 ub = hb[(size_t)ed.y * RU2 + lane];
        float d = blo(ua.x) * blo(ub.x) * wd.x + bhi(ua.x) * bhi(ub.x) * wd.y
                + blo(ua.y) * blo(ub.y) * wd.z + bhi(ua.y) * bhi(ub.y) * wd.w;
        #pragma unroll
        for (int m = 32; m > 0; m >>= 1) d += __shfl_xor(d, m, 64);
        if (lane == 0) {
            const float p1 = 1.0f / (1.0f + __expf(-(d + bd)));
            out[e] = make_float2(1.0f - p1, p1);
        }
    }
}

__global__ __launch_bounds__(256) void edge_predict_f32(
    const float* __restrict__ h, const int2* __restrict__ edges,
    const float* __restrict__ wc, float2* __restrict__ out, int E)
{
    const int lane = threadIdx.x & 63;
    const int wid  = blockIdx.x * (blockDim.x >> 6) + (threadIdx.x >> 6);
    const int nw   = gridDim.x * (blockDim.x >> 6);
    const float4 wd = ((const float4*)wc)[lane];
    const float  bd = wc[256];
    for (int e = wid; e < E; e += nw) {
        const int2 ed = edges[e];
        const float4 a = ((const float4*)(h + (size_t)ed.x * D))[lane];
        const float4 b = ((const float4*)(h + (size_t)ed.y * D))[lane];
        float d = a.x * b.x * wd.x + a.y * b.y * wd.y + a.z * b.z * wd.z + a.w * b.w * wd.w;
        #pragma unroll
        for (int m = 32; m > 0; m >>= 1) d += __shfl_xor(d, m, 64);
        if (lane == 0) {
            const float p1 = 1.0f / (1.0f + __expf(-(d + bd)));
            out[e] = make_float2(1.0f - p1, p1);
        }
    }
}

// ---------------------------------------------------------------------------
extern "C" void kernel_launch(void* const* d_in, const int* in_sizes, int n_in,
                              void* d_out, int out_size, void* d_ws, size_t ws_size,
                              hipStream_t stream)
{
    const float* h     = (const float*)d_in[0];
    const int2*  edges = (const int2*)d_in[1];
    const float* W1    = (const float*)d_in[2];
    const float* b1    = (const float*)d_in[3];
    const float* W2    = (const float*)d_in[4];
    const float* b2    = (const float*)d_in[5];
    const float* W3    = (const float*)d_in[6];
    const float* b3    = (const float*)d_in[7];
    float2* out = (float2*)d_out;

    const int nNodes = in_sizes[0] / D;
    const int E      = in_sizes[1] / 2;
    const int nvec   = nNodes * DV;

    // ws carve-up (all 16B-aligned)
    const int    nblk1  = (nNodes + 255) / 256;
    const int    nhp    = nblk1 * 256;
    const size_t wcB    = 2048;
    const size_t tblB   = (size_t)nNodes * D * 2;
    const size_t puvB   = (size_t)E * 8;
    const size_t pidxB  = (size_t)E * 4;
    const size_t histB  = (size_t)nhp * 4;
    const size_t auxB   = 4096;

    char* p = (char*)d_ws;
    float* wc     = (float*)p;                p += wcB;
    uint2* hb     = (uint2*)p;                p += tblB;
    const size_t needBf16 = (size_t)(p - (char*)d_ws);
    int2*  puv    = (int2*)p;                 p += puvB;
    int*   pidx   = (int*)p;                  p += pidxB;
    int*   hist   = (int*)p;                  p += histB;
    int*   cursor = (int*)p;                  p += histB;
    int*   aux    = (int*)p;                  p += auxB;
    const size_t needSort = (size_t)(p - (char*)d_ws);

    if (ws_size >= needSort && nblk1 <= 1024) {
        prep<<<4096, 256, 0, stream>>>((const float4*)h, hb, nvec,
                                       W1, b1, W2, b2, W3, b3, wc, hist, nhp);
        hist_k<<<2048, 256, 0, stream>>>(edges, hist, E);
        scan1<<<nblk1, 256, 0, stream>>>(hist, cursor, aux, nNodes);
        scan2<<<1, 256, 0, stream>>>(aux, nblk1);
        scan3<<<nblk1, 256, 0, stream>>>(cursor, aux, nNodes);
        scatter_k<<<2048, 256, 0, stream>>>(edges, cursor, puv, pidx, E);
        const int nw = 2048 * 4;
        const int chunk = (E + nw - 1) / nw;
        edge_sorted<<<2048, 256, 0, stream>>>(hb, puv, pidx, wc, out, E, chunk);
    } else if (ws_size >= needBf16) {
        prep<<<4096, 256, 0, stream>>>((const float4*)h, hb, nvec,
                                       W1, b1, W2, b2, W3, b3, wc, hist, 0);
        edge_predict_bf16<<<2048, 256, 0, stream>>>(hb, edges, wc, out, E);
    } else {
        prep<<<4096, 256, 0, stream>>>((const float4*)h, (uint2*)wc /*unused*/, 0,
                                       W1, b1, W2, b2, W3, b3, wc, hist, 0);
        edge_predict_f32<<<2048, 256, 0, stream>>>(h, edges, wc, out, E);
    }
}

// Round 4
// 315.669 us; speedup vs baseline: 1.3686x; 1.3686x over previous
//
#include <hip/hip_runtime.h>
#include <hip/hip_bf16.h>

// EdgePredict: out = softmax((h[u]*h[v]) @ W1 @ W2 @ W3 + biases)
// R0: linear MLP chain collapses to wd[256] + bd; 2-class softmax = sigmoid
//     of the logit difference.
// R2: f16/bf16 table in ws halves gather bytes (edge kernel 288 -> 151 us).
// R3 post-mortem: sorting halved FETCH but edge kernel stayed ~155 us at 59%
//     VALUBusy -> per-edge VALU/shuffle work is the wall, not bytes. Sort's
//     6 extra dispatches cost ~100 us. Dropped.
// R4: MFMA dot products. 16 edges/wave, A = h[u]*wd (f16), B = h[v] (f16),
//     8x mfma_f32_16x16x32_f16 over K=256; the 16 logit-diffs are diag(C).
//     Per edge: 1 dwordx4 + 0.5 MFMA + ~3 VALU (vs ~35 VALU + 6 DS).

#define D 256

typedef _Float16 half8 __attribute__((ext_vector_type(8)));
typedef float float4v __attribute__((ext_vector_type(4)));

// ---------------------------------------------------------------------------
// prep: convert h (fp32) -> packed f16 table in ws; block 0 additionally
// collapses the weight chain into wd[256] (f32 + f16 copies) and bd.
// ws layout: [0,1152) wc: f32 wd[256] + bd at idx 256
//            [1280,1792) wdf: f16 wd[256]
//            [2048, ...) f16 table, 512 B/row
// ---------------------------------------------------------------------------
__global__ __launch_bounds__(256) void prep(
    const float4* __restrict__ h, half8* __restrict__ tb, int nv8,
    const float* __restrict__ W1, const float* __restrict__ b1,
    const float* __restrict__ W2, const float* __restrict__ b2,
    const float* __restrict__ W3, const float* __restrict__ b3,
    float* __restrict__ wc, _Float16* __restrict__ wdf)
{
    if (blockIdx.x == 0) {
        __shared__ float T[128][2];  // T = W2 @ W3
        const int t = threadIdx.x;
        {
            const int j = t >> 1, c = t & 1;
            float s = 0.f;
            #pragma unroll 8
            for (int k = 0; k < 64; ++k) s += W2[j * 64 + k] * W3[k * 2 + c];
            T[j][c] = s;
        }
        __syncthreads();
        float s0 = 0.f, s1 = 0.f;
        #pragma unroll 8
        for (int j = 0; j < 128; ++j) {
            const float w = W1[t * 128 + j];
            s0 += w * T[j][0];
            s1 += w * T[j][1];
        }
        const float wd = s1 - s0;
        wc[t]  = wd;
        wdf[t] = (_Float16)wd;
        if (t == 0) {
            float f0 = b3[0], f1 = b3[1];
            for (int j = 0; j < 128; ++j) { f0 += b1[j] * T[j][0]; f1 += b1[j] * T[j][1]; }
            for (int k = 0; k < 64; ++k)  { f0 += b2[k] * W3[k * 2 + 0]; f1 += b2[k] * W3[k * 2 + 1]; }
            wc[256] = f1 - f0;  // bd
        }
    }

    const int gstride = gridDim.x * blockDim.x;
    for (int i = blockIdx.x * blockDim.x + threadIdx.x; i < nv8; i += gstride) {
        const float4 f0 = h[2 * i];
        const float4 f1 = h[2 * i + 1];
        half8 o;
        o[0] = (_Float16)f0.x; o[1] = (_Float16)f0.y;
        o[2] = (_Float16)f0.z; o[3] = (_Float16)f0.w;
        o[4] = (_Float16)f1.x; o[5] = (_Float16)f1.y;
        o[6] = (_Float16)f1.z; o[7] = (_Float16)f1.w;
        tb[i] = o;
    }
}

// ---------------------------------------------------------------------------
// MFMA edge kernel: one wave per 16-edge group (grid-stride).
// A[m][k] = tbl[u_m][k] * wd[k], m = lane&15, k = quad*8+j  (quad = lane>>4)
// B[k][n] = tbl[v_n][k],         n = lane&15, same k pattern
// C diag:  col = lane&15, row = quad*4 + reg; edge e lives in lane
//          16*(e>>2)+e, reg e&3  ->  lanes with quad == (lane&15)>>2.
// ---------------------------------------------------------------------------
__global__ __launch_bounds__(256) void edge_mfma(
    const _Float16* __restrict__ tbl, const int2* __restrict__ edges,
    const float* __restrict__ wc, const _Float16* __restrict__ wdf,
    float2* __restrict__ out, int E, int ngroups)
{
    const int lane = threadIdx.x & 63;
    const int m    = lane & 15;
    const int quad = lane >> 4;
    const int wid  = blockIdx.x * (blockDim.x >> 6) + (threadIdx.x >> 6);
    const int nw   = gridDim.x * (blockDim.x >> 6);

    const float bd = wc[256];
    const bool diag = (quad == (m >> 2));

    // loop-invariant wd fragments for all 8 k-blocks (32 VGPRs)
    half8 wq[8];
    {
        const half8* wp = (const half8*)(wdf + quad * 8);
        #pragma unroll
        for (int s = 0; s < 8; ++s) wq[s] = wp[4 * s];
    }

    for (int g = wid; g < ngroups; g += nw) {
        const int em = g * 16 + m;
        const int2 ed = edges[min(em, E - 1)];
        const half8* pa = (const half8*)(tbl + (size_t)ed.x * D + quad * 8);
        const half8* pb = (const half8*)(tbl + (size_t)ed.y * D + quad * 8);

        float4v acc = {0.f, 0.f, 0.f, 0.f};
        #pragma unroll
        for (int s = 0; s < 8; ++s) {
            const half8 a = pa[4 * s] * wq[s];   // 4x v_pk_mul_f16
            const half8 b = pb[4 * s];
            acc = __builtin_amdgcn_mfma_f32_16x16x32_f16(a, b, acc, 0, 0, 0);
        }

        if (diag && em < E) {
            const float d  = acc[m & 3] + bd;
            const float p1 = 1.0f / (1.0f + __expf(-d));
            out[em] = make_float2(1.0f - p1, p1);
        }
    }
}

// ---------------------------------------------------------------------------
// Fallback if ws can't hold the table: fp32 gather + wave reduction (R1-style)
// ---------------------------------------------------------------------------
__global__ __launch_bounds__(256) void edge_predict_f32(
    const float* __restrict__ h, const int2* __restrict__ edges,
    const float* __restrict__ wc, float2* __restrict__ out, int E)
{
    const int lane = threadIdx.x & 63;
    const int wid  = blockIdx.x * (blockDim.x >> 6) + (threadIdx.x >> 6);
    const int nw   = gridDim.x * (blockDim.x >> 6);
    const float4 wd = ((const float4*)wc)[lane];
    const float  bd = wc[256];
    for (int e = wid; e < E; e += nw) {
        const int2 ed = edges[e];
        const float4 a = ((const float4*)(h + (size_t)ed.x * D))[lane];
        const float4 b = ((const float4*)(h + (size_t)ed.y * D))[lane];
        float d = a.x * b.x * wd.x + a.y * b.y * wd.y + a.z * b.z * wd.z + a.w * b.w * wd.w;
        #pragma unroll
        for (int mm = 32; mm > 0; mm >>= 1) d += __shfl_xor(d, mm, 64);
        if (lane == 0) {
            const float p1 = 1.0f / (1.0f + __expf(-(d + bd)));
            out[e] = make_float2(1.0f - p1, p1);
        }
    }
}

// ---------------------------------------------------------------------------
extern "C" void kernel_launch(void* const* d_in, const int* in_sizes, int n_in,
                              void* d_out, int out_size, void* d_ws, size_t ws_size,
                              hipStream_t stream)
{
    const float* h     = (const float*)d_in[0];
    const int2*  edges = (const int2*)d_in[1];
    const float* W1    = (const float*)d_in[2];
    const float* b1    = (const float*)d_in[3];
    const float* W2    = (const float*)d_in[4];
    const float* b2    = (const float*)d_in[5];
    const float* W3    = (const float*)d_in[6];
    const float* b3    = (const float*)d_in[7];
    float2* out = (float2*)d_out;

    const int nNodes = in_sizes[0] / D;
    const int E      = in_sizes[1] / 2;

    float*     wc  = (float*)d_ws;                       // f32 wd[256] + bd
    _Float16*  wdf = (_Float16*)((char*)d_ws + 1280);    // f16 wd[256]
    _Float16*  tbl = (_Float16*)((char*)d_ws + 2048);    // f16 table
    const size_t need = 2048 + (size_t)nNodes * D * 2;

    if (ws_size >= need) {
        const int nv8 = nNodes * (D / 8);
        prep<<<4096, 256, 0, stream>>>((const float4*)h, (half8*)tbl, nv8,
                                       W1, b1, W2, b2, W3, b3, wc, wdf);
        const int ngroups = (E + 15) / 16;
        edge_mfma<<<2048, 256, 0, stream>>>(tbl, edges, wc, wdf, out, E, ngroups);
    } else {
        prep<<<1, 256, 0, stream>>>((const float4*)h, (half8*)wc /*unused*/, 0,
                                    W1, b1, W2, b2, W3, b3, wc, wdf);
        edge_predict_f32<<<2048, 256, 0, stream>>>(h, edges, wc, out, E);
    }
}